// Round 2
// baseline (274.160 us; speedup 1.0000x reference)
//
#include <hip/hip_runtime.h>
#include <math.h>

// Problem constants
#define NB   64
#define TT   2048
// Tail-window truncation: output = x[:, 2047]; the only temporal coupling is
// the LIF membrane (decay 0.5/step + hard reset). v(T0)=0 direct error at
// 2047 is 0.5^63; validated in prior rounds (TW=192 matched full scan).
#define TW   64
#define T0   (TT - TW)     // 1984
#define NR   (NB * TW)     // 4096 active rows

__device__ __forceinline__ float gelu_exact(float x) {
    return 0.5f * x * (1.0f + erff(x * 0.7071067811865476f));
}

// One block per batch (the whole network is batch-independent: GEMMs/LN are
// per-row, LIF chains and residual live inside one batch). 64 blocks x 512
// threads; all phases separated by __syncthreads. LDS (64KB) is timeshared:
// W staging <-> H/Y tiles <-> projector G+pw2. X and Spk use DISTINCT
// per-layer global regions so no address is ever re-read after being
// rewritten (keeps scalar-cache use safe and restrict views honest).
__global__ void __launch_bounds__(512) fused_kernel(
    const float* __restrict__ hist,
    const float* __restrict__ pw1, const float* __restrict__ pb1,
    const float* __restrict__ pw2, const float* __restrict__ pb2,
    const float* __restrict__ fc1w, const float* __restrict__ fc1b,
    const float* __restrict__ n1g,  const float* __restrict__ n1b,
    const float* __restrict__ fc2w, const float* __restrict__ fc2b,
    const float* __restrict__ n2g,  const float* __restrict__ n2b,
    const float* __restrict__ Xr,  float* __restrict__ Xw,
    const float* __restrict__ SpkR, float* __restrict__ SpkW,
    float* __restrict__ out)
{
    __shared__ float LB[64*256];     // 64KB, timeshared across phases
    const int wave = threadIdx.x >> 6, lane = threadIdx.x & 63;
    const int b = blockIdx.x;
    const int rbl = wave * 8;        // block-local row base for this wave
    const int rb  = __builtin_amdgcn_readfirstlane(b*64 + wave*8);

    // ---------------- proj1: G = gelu(hist_b @ pw1 + pb1) -> LB[0..4096)
    //                  and stage pw2 (32KB) -> LB[4096..12288)
    {
        const float* hb = hist + ((size_t)b * TT + T0) * 4;
        float w0 = pw1[lane], w1 = pw1[64+lane], w2 = pw1[128+lane], w3 = pw1[192+lane];
        float bb = pb1[lane];
        #pragma unroll
        for (int r = 0; r < 8; ++r) {
            int t = rbl + r;
            float4 h = *(const float4*)(hb + t*4);          // wave-uniform row
            LB[t*64 + lane] = gelu_exact(bb + h.x*w0 + h.y*w1 + h.z*w2 + h.w*w3);
        }
        for (int i = threadIdx.x; i < 2048; i += 512)
            ((float4*)(LB + 4096))[i] = ((const float4*)pw2)[i];
    }
    __syncthreads();
    // ---------------- proj2: X0 = G @ pw2 + pb2  (G, pw2 both in LDS)
    {
        float2 bv = ((const float2*)pb2)[lane];
        float2 acc[8];
        #pragma unroll
        for (int r = 0; r < 8; ++r) acc[r] = make_float2(0.f, 0.f);
        #pragma unroll 2
        for (int k4 = 0; k4 < 16; ++k4) {
            float4 xr[8];
            #pragma unroll
            for (int r = 0; r < 8; ++r)
                xr[r] = *(const float4*)(LB + (rbl + r)*64 + k4*4);  // uniform ds_read
            #pragma unroll
            for (int kk = 0; kk < 4; ++kk) {
                float2 w = ((const float2*)(LB + 4096 + (k4*4 + kk)*128))[lane];
                #pragma unroll
                for (int r = 0; r < 8; ++r) {
                    float xv = ((const float*)&xr[r])[kk];
                    acc[r].x += xv * w.x;
                    acc[r].y += xv * w.y;
                }
            }
        }
        #pragma unroll
        for (int r = 0; r < 8; ++r) {
            float2 o; o.x = acc[r].x + bv.x; o.y = acc[r].y + bv.y;
            ((float2*)(Xw + (size_t)(rb + r) * 128))[lane] = o;
        }
    }

    #pragma unroll 1
    for (int l = 0; l < 4; ++l) {
        const float* __restrict__ Xl   = Xr  + (size_t)l     * NR * 128;
        float*       __restrict__ Xo   = Xw  + (size_t)(l+1) * NR * 128;
        const float* __restrict__ SpRl = SpkR + (size_t)l * NR * 256;
        float*       __restrict__ SpWl = SpkW + (size_t)l * NR * 256;

        // ---- fc1 + LN -> H tile in LDS -> LIF1 -> spikes to global ----
        {
            const float* W = fc1w + (size_t)l * 128 * 256;
            float4 bv  = ((const float4*)(fc1b + l*256))[lane];
            float4 gv  = ((const float4*)(n1g  + l*256))[lane];
            float4 btv = ((const float4*)(n1b  + l*256))[lane];
            const float* x0 = Xl + (size_t)rb * 128;
            float4 acc[8];
            #pragma unroll
            for (int r = 0; r < 8; ++r) acc[r] = make_float4(0.f,0.f,0.f,0.f);
            for (int h = 0; h < 2; ++h) {
                __syncthreads();                          // prev-phase LB readers done
                const float4* Wh = (const float4*)(W + h*64*256);
                for (int i = threadIdx.x; i < 4096; i += 512)
                    ((float4*)LB)[i] = Wh[i];
                __syncthreads();
                const float* xh = x0 + h*64;
                #pragma unroll 2
                for (int k4 = 0; k4 < 16; ++k4) {
                    float4 xr[8];
                    #pragma unroll
                    for (int r = 0; r < 8; ++r)
                        xr[r] = *(const float4*)(xh + r*128 + k4*4);  // uniform row load
                    #pragma unroll
                    for (int kk = 0; kk < 4; ++kk) {
                        float4 w = ((const float4*)(LB + (k4*4 + kk)*256))[lane];
                        #pragma unroll
                        for (int r = 0; r < 8; ++r) {
                            float xv = ((const float*)&xr[r])[kk];
                            acc[r].x += xv * w.x; acc[r].y += xv * w.y;
                            acc[r].z += xv * w.z; acc[r].w += xv * w.w;
                        }
                    }
                }
            }
            #pragma unroll
            for (int r = 0; r < 8; ++r) {
                float4 a = acc[r];
                a.x += bv.x; a.y += bv.y; a.z += bv.z; a.w += bv.w;
                float s = a.x + a.y + a.z + a.w;
                #pragma unroll
                for (int m = 1; m < 64; m <<= 1) s += __shfl_xor(s, m, 64);
                float mean = s * (1.0f/256.0f);
                float dx = a.x - mean, dy = a.y - mean, dz = a.z - mean, dw = a.w - mean;
                float q2 = dx*dx + dy*dy + dz*dz + dw*dw;
                #pragma unroll
                for (int m = 1; m < 64; m <<= 1) q2 += __shfl_xor(q2, m, 64);
                float inv = 1.0f / sqrtf(q2 * (1.0f/256.0f) + 1e-5f);
                acc[r].x = dx*inv*gv.x + btv.x; acc[r].y = dy*inv*gv.y + btv.y;
                acc[r].z = dz*inv*gv.z + btv.z; acc[r].w = dw*inv*gv.w + btv.w;
            }
            __syncthreads();                 // all waves done reading W in LB
            #pragma unroll
            for (int r = 0; r < 8; ++r)
                ((float4*)(LB + (rbl + r)*256))[lane] = acc[r];   // H tile -> LDS
            __syncthreads();
            if (threadIdx.x < 256) {         // LIF1: column chains over the window
                int d = threadIdx.x;
                float* sp = SpWl + (size_t)b * 64 * 256 + d;
                float v = 0.f;
                #pragma unroll 8
                for (int t = 0; t < 64; ++t) {
                    float x = LB[t*256 + d];
                    v += (x - v) * 0.5f;
                    bool s = (v >= 1.f);
                    sp[t*256] = s ? 1.f : 0.f;
                    v = s ? 0.f : v;
                }
            }
        }
        // ---- fc2 + LN -> Y tile in LDS -> LIF2 + residual -> X(l+1) ----
        {
            const float* W = fc2w + (size_t)l * 256 * 128;
            float2 bv  = ((const float2*)(fc2b + l*128))[lane];
            float2 gv  = ((const float2*)(n2g  + l*128))[lane];
            float2 btv = ((const float2*)(n2b  + l*128))[lane];
            const float* x0 = SpRl + (size_t)rb * 256;
            float2 acc[8];
            #pragma unroll
            for (int r = 0; r < 8; ++r) acc[r] = make_float2(0.f, 0.f);
            for (int h = 0; h < 2; ++h) {
                __syncthreads();                          // LIF1 LB readers done
                const float4* Wh = (const float4*)(W + h*128*128);
                for (int i = threadIdx.x; i < 4096; i += 512)
                    ((float4*)LB)[i] = Wh[i];
                __syncthreads();
                const float* xh = x0 + h*128;
                #pragma unroll 2
                for (int k4 = 0; k4 < 32; ++k4) {
                    float4 xr[8];
                    #pragma unroll
                    for (int r = 0; r < 8; ++r)
                        xr[r] = *(const float4*)(xh + r*256 + k4*4);
                    #pragma unroll
                    for (int kk = 0; kk < 4; ++kk) {
                        float2 w = ((const float2*)(LB + (k4*4 + kk)*128))[lane];
                        #pragma unroll
                        for (int r = 0; r < 8; ++r) {
                            float xv = ((const float*)&xr[r])[kk];
                            acc[r].x += xv * w.x;
                            acc[r].y += xv * w.y;
                        }
                    }
                }
            }
            #pragma unroll
            for (int r = 0; r < 8; ++r) {
                float2 a = acc[r];
                a.x += bv.x; a.y += bv.y;
                float s = a.x + a.y;
                #pragma unroll
                for (int m = 1; m < 64; m <<= 1) s += __shfl_xor(s, m, 64);
                float mean = s * (1.0f/128.0f);
                float dx = a.x - mean, dy = a.y - mean;
                float q = dx*dx + dy*dy;
                #pragma unroll
                for (int m = 1; m < 64; m <<= 1) q += __shfl_xor(q, m, 64);
                float inv = 1.0f / sqrtf(q * (1.0f/128.0f) + 1e-5f);
                acc[r].x = dx*inv*gv.x + btv.x;
                acc[r].y = dy*inv*gv.y + btv.y;
            }
            __syncthreads();                 // all waves done reading W in LB
            #pragma unroll
            for (int r = 0; r < 8; ++r)
                ((float2*)(LB + (rbl + r)*128))[lane] = acc[r];   // Y tile -> LDS
            __syncthreads();
            if (threadIdx.x < 128) {         // LIF2 + residual into X(l+1)
                int n = threadIdx.x;
                const float* xi = Xl + (size_t)b * 64 * 128 + n;
                float*       xo = Xo + (size_t)b * 64 * 128 + n;
                float v = 0.f, xlast = 0.f;
                #pragma unroll 8
                for (int t = 0; t < 64; ++t) {
                    float y = LB[t*128 + n];
                    v += (y - v) * 0.5f;
                    bool s = (v >= 1.f);
                    float xn = xi[t*128] + (s ? 1.f : 0.f);
                    xo[t*128] = xn;
                    xlast = xn;
                    v = s ? 0.f : v;
                }
                if (l == 3) out[b * 128 + n] = xlast;    // row t=2047 per (b,n)
            }
        }
    }
}

extern "C" void kernel_launch(void* const* d_in, const int* in_sizes, int n_in,
                              void* d_out, int out_size, void* d_ws, size_t ws_size,
                              hipStream_t stream) {
    const float* hist = (const float*)d_in[0];
    const float* pw1  = (const float*)d_in[1];
    const float* pb1  = (const float*)d_in[2];
    const float* pw2  = (const float*)d_in[3];
    const float* pb2  = (const float*)d_in[4];
    const float* fc1w = (const float*)d_in[5];
    const float* fc1b = (const float*)d_in[6];
    const float* n1g  = (const float*)d_in[7];
    const float* n1b  = (const float*)d_in[8];
    const float* fc2w = (const float*)d_in[9];
    const float* fc2b = (const float*)d_in[10];
    const float* n2g  = (const float*)d_in[11];
    const float* n2b  = (const float*)d_in[12];
    float* out = (float*)d_out;

    char* ws = (char*)d_ws;
    float* Xbuf = (float*)ws;                    // 5 regions x [NR,128] = 10 MiB
    float* Spb  = (float*)(ws + (16ull << 20));  // 4 regions x [NR,256] = 16 MiB

    fused_kernel<<<64, 512, 0, stream>>>(hist, pw1, pb1, pw2, pb2,
                                         fc1w, fc1b, n1g, n1b,
                                         fc2w, fc2b, n2g, n2b,
                                         Xbuf, Xbuf, Spb, Spb, out);
}